// Round 1
// baseline (822.827 us; speedup 1.0000x reference)
//
#include <hip/hip_runtime.h>
#include <stdint.h>

#define N_NODES 50000
#define N_EDGES 800000
#define EDGE_TILES (N_EDGES / 64)   // 12500
#define NODE_TILES 782              // ceil(50000/64), last tile has 16 rows

// edge GEMM1: K = 266 padded to 288 (9 * 32)
#define K1   266
#define K1P  288
#define SA   296   // A-tile row stride (bf16 elems): 592B, odd*16B -> <=2-way bank conflicts
#define SW1  296
#define SE   72    // e-tile stride
#define SW2  72

// node kernels
#define SA1  200   // node1 A stride (K=192)
#define SN1  200
#define SA2  264   // node2 A stride (K=256)
#define SN2  264

typedef short bf16x8 __attribute__((ext_vector_type(8)));
typedef float f32x4  __attribute__((ext_vector_type(4)));

static __device__ __forceinline__ unsigned short f2bf(float f) {
  unsigned int x = __float_as_uint(f);
  unsigned int r = (x + 0x7fffu + ((x >> 16) & 1u)) >> 16;
  return (unsigned short)r;
}
static __device__ __forceinline__ float bf2f(unsigned short u) {
  return __uint_as_float(((unsigned int)u) << 16);
}
static __device__ __forceinline__ float silu_f(float x) {
  return x / (1.0f + __expf(-x));
}
static __device__ __forceinline__ bf16x8 pack8(float4 u, float4 v) {
  bf16x8 w;
  w[0] = (short)f2bf(u.x); w[1] = (short)f2bf(u.y);
  w[2] = (short)f2bf(u.z); w[3] = (short)f2bf(u.w);
  w[4] = (short)f2bf(v.x); w[5] = (short)f2bf(v.y);
  w[6] = (short)f2bf(v.z); w[7] = (short)f2bf(v.w);
  return w;
}

// ---------------------------------------------------------------------------
// Kernel 1: edge phase. Tiles of 64 edges. Computes gated e_msg and
// atomically accumulates into agg[N][64] (f32, in workspace).
// ---------------------------------------------------------------------------
__global__ __launch_bounds__(256, 1) void edge_kernel(
    const float* __restrict__ H, const float* __restrict__ xyz,
    const int* __restrict__ eidx, const float* __restrict__ estruct,
    const float* __restrict__ erest,
    const float* __restrict__ We1, const float* __restrict__ be1,
    const float* __restrict__ We2, const float* __restrict__ be2,
    const float* __restrict__ Wg1, const float* __restrict__ bg1,
    const float* __restrict__ Wg2, const float* __restrict__ bg2,
    float* __restrict__ agg)
{
  __shared__ unsigned short Asm[64 * SA];   // e_in tile, bf16
  __shared__ unsigned short W1s[64 * SW1];  // We1^T [n][k]
  __shared__ unsigned short Es [64 * SE];   // e tile after silu, bf16
  __shared__ unsigned short W2s[64 * SW2];  // We2^T [n][k]
  __shared__ float d2s[64];                 // dist2 (f32, rank-1 correction)
  __shared__ float dls[64];                 // delta (f32, rank-1 correction)
  __shared__ float gsm[64];                 // gate value per edge
  __shared__ float gpart[64][4];

  const int tid  = threadIdx.x;
  const int lane = tid & 63;
  const int wv   = tid >> 6;     // wave id 0..3
  const int lr   = lane & 15;
  const int lq   = lane >> 4;
  const int m0   = wv * 16;

  // ---- stage transposed weights (once per block) ----
  {
    int n = tid & 63, chunk = tid >> 6;
    for (int k = chunk * 72; k < chunk * 72 + 72; ++k)
      W1s[n * SW1 + k] = (k < K1) ? f2bf(We1[k * 64 + n]) : (unsigned short)0;
    for (int k = chunk * 16; k < chunk * 16 + 16; ++k)
      W2s[n * SW2 + k] = f2bf(We2[k * 64 + n]);
  }
  if (tid < 64) {
    for (int k = K1; k < K1P; ++k) Asm[tid * SA + k] = 0;  // zero K pad
  }
  __syncthreads();

  for (int tile = blockIdx.x; tile < EDGE_TILES; tile += gridDim.x) {
    const int e0 = tile * 64;

    // ---- stage A-tile: [Hi | Hj | 0 | 0 | struct] as bf16 ----
    {
      int le = tid >> 2, part = tid & 3;
      int e = e0 + le;
      int node = (part < 2) ? eidx[e] : eidx[N_EDGES + e];
      const float* src = H + (long)node * 128 + (part & 1) * 64;
      unsigned short* dst = &Asm[le * SA + part * 64];
      #pragma unroll
      for (int q = 0; q < 64; q += 8) {
        float4 u = *(const float4*)(src + q);
        float4 v = *(const float4*)(src + q + 4);
        *(bf16x8*)(dst + q) = pack8(u, v);
      }
    }
    if (tid < 64) {
      int e = e0 + tid;
      int ni = eidx[e], nj = eidx[N_EDGES + e];
      float dx = xyz[ni * 3 + 0] - xyz[nj * 3 + 0];
      float dy = xyz[ni * 3 + 1] - xyz[nj * 3 + 1];
      float dz = xyz[ni * 3 + 2] - xyz[nj * 3 + 2];
      float d2 = dx * dx + dy * dy + dz * dz;
      float dist = sqrtf(d2 + 1e-9f);
      float rest = erest[e];
      float delta = (dist - rest) / (rest + 1e-9f);
      d2s[tid] = d2;
      dls[tid] = delta;
      Asm[tid * SA + 256] = 0;   // handled as f32 rank-1 correction
      Asm[tid * SA + 257] = 0;
    } else if (tid < 128) {
      int le = tid - 64, e = e0 + le;
      #pragma unroll
      for (int q = 0; q < 8; ++q)
        Asm[le * SA + 258 + q] = f2bf(estruct[e * 8 + q]);
    }
    __syncthreads();

    // ---- gate MLP in fp32: [d2, delta, struct] -> 32 -> 1 -> sigmoid ----
    {
      int le = tid & 63, part = tid >> 6;
      float gin[10];
      gin[0] = d2s[le];
      gin[1] = dls[le];
      #pragma unroll
      for (int k = 0; k < 8; ++k) gin[2 + k] = bf2f(Asm[le * SA + 258 + k]);
      float partial = 0.f;
      #pragma unroll
      for (int hh = 0; hh < 8; ++hh) {
        int h = part * 8 + hh;
        float a = bg1[h];
        #pragma unroll
        for (int k = 0; k < 10; ++k) a += gin[k] * Wg1[k * 32 + h];
        partial += silu_f(a) * Wg2[h];
      }
      gpart[le][part] = partial;
    }
    __syncthreads();
    if (tid < 64) {
      float s = gpart[tid][0] + gpart[tid][1] + gpart[tid][2] + gpart[tid][3] + bg2[0];
      gsm[tid] = 1.f / (1.f + __expf(-s));
    }

    // ---- GEMM1: e = silu(e_in @ We1 + be1 + rank-1 fp32 corrections) ----
    f32x4 zero4 = {0.f, 0.f, 0.f, 0.f};
    f32x4 acc[4];
    #pragma unroll
    for (int f = 0; f < 4; ++f) acc[f] = zero4;
    #pragma unroll
    for (int s = 0; s < 9; ++s) {
      int kb = s * 32 + lq * 8;
      bf16x8 a = *(const bf16x8*)&Asm[(m0 + lr) * SA + kb];
      #pragma unroll
      for (int f = 0; f < 4; ++f) {
        bf16x8 b = *(const bf16x8*)&W1s[(f * 16 + lr) * SW1 + kb];
        acc[f] = __builtin_amdgcn_mfma_f32_16x16x32_bf16(a, b, acc[f], 0, 0, 0);
      }
    }
    #pragma unroll
    for (int f = 0; f < 4; ++f) {
      int n = f * 16 + lr;
      float bias = be1[n];
      float w256 = We1[256 * 64 + n];
      float w257 = We1[257 * 64 + n];
      #pragma unroll
      for (int r = 0; r < 4; ++r) {
        int m = m0 + lq * 4 + r;
        float v = acc[f][r] + bias + d2s[m] * w256 + dls[m] * w257;
        Es[m * SE + n] = f2bf(silu_f(v));
      }
    }
    __syncthreads();  // Es + gsm visible to all

    // ---- GEMM2: e_msg = silu(e @ We2 + be2) * g; scatter-add ----
    f32x4 acc2[4];
    #pragma unroll
    for (int f = 0; f < 4; ++f) acc2[f] = zero4;
    #pragma unroll
    for (int s = 0; s < 2; ++s) {
      int kb = s * 32 + lq * 8;
      bf16x8 a = *(const bf16x8*)&Es[(m0 + lr) * SE + kb];
      #pragma unroll
      for (int f = 0; f < 4; ++f) {
        bf16x8 b = *(const bf16x8*)&W2s[(f * 16 + lr) * SW2 + kb];
        acc2[f] = __builtin_amdgcn_mfma_f32_16x16x32_bf16(a, b, acc2[f], 0, 0, 0);
      }
    }
    #pragma unroll
    for (int f = 0; f < 4; ++f) {
      int n = f * 16 + lr;
      float b2 = be2[n];
      #pragma unroll
      for (int r = 0; r < 4; ++r) {
        int m = m0 + lq * 4 + r;
        int dest = eidx[e0 + m];  // i = edge_index[0]
        float v = silu_f(acc2[f][r] + b2) * gsm[m];
        atomicAdd(agg + (long)dest * 64 + n, v);
      }
    }
    __syncthreads();
  }
}

// ---------------------------------------------------------------------------
// Kernel 2: h1 = silu([H | agg] @ Wn1 + bn1), stored bf16 to workspace
// ---------------------------------------------------------------------------
__global__ __launch_bounds__(256, 1) void node1_kernel(
    const float* __restrict__ H, const float* __restrict__ agg,
    const float* __restrict__ Wn1, const float* __restrict__ bn1,
    unsigned short* __restrict__ h1)
{
  __shared__ unsigned short As[64 * SA1];
  __shared__ unsigned short Ws[256 * SN1];  // Wn1^T [n][k], n=0..255, k=0..191

  const int tid  = threadIdx.x;
  const int lane = tid & 63;
  const int wv   = tid >> 6;
  const int lr   = lane & 15;
  const int lq   = lane >> 4;
  const int m0   = wv * 16;
  const int n0   = blockIdx.x * 64;

  {
    int n = tid;
    for (int k = 0; k < 192; ++k)
      Ws[n * SN1 + k] = f2bf(Wn1[k * 256 + n]);
  }
  {
    int le = tid >> 2, part = tid & 3;
    int node = n0 + le; if (node >= N_NODES) node = N_NODES - 1;
    if (part < 2) {
      const float* src = H + (long)node * 128 + part * 64;
      unsigned short* dst = &As[le * SA1 + part * 64];
      #pragma unroll
      for (int q = 0; q < 64; q += 8) {
        float4 u = *(const float4*)(src + q);
        float4 v = *(const float4*)(src + q + 4);
        *(bf16x8*)(dst + q) = pack8(u, v);
      }
    } else if (part == 2) {
      const float* src = agg + (long)node * 64;
      unsigned short* dst = &As[le * SA1 + 128];
      #pragma unroll
      for (int q = 0; q < 64; q += 8) {
        float4 u = *(const float4*)(src + q);
        float4 v = *(const float4*)(src + q + 4);
        *(bf16x8*)(dst + q) = pack8(u, v);
      }
    }
  }
  __syncthreads();

  f32x4 zero4 = {0.f, 0.f, 0.f, 0.f};
  f32x4 acc[16];
  #pragma unroll
  for (int f = 0; f < 16; ++f) acc[f] = zero4;
  #pragma unroll
  for (int s = 0; s < 6; ++s) {
    int kb = s * 32 + lq * 8;
    bf16x8 a = *(const bf16x8*)&As[(m0 + lr) * SA1 + kb];
    #pragma unroll
    for (int f = 0; f < 16; ++f) {
      bf16x8 b = *(const bf16x8*)&Ws[(f * 16 + lr) * SN1 + kb];
      acc[f] = __builtin_amdgcn_mfma_f32_16x16x32_bf16(a, b, acc[f], 0, 0, 0);
    }
  }
  #pragma unroll
  for (int f = 0; f < 16; ++f) {
    int n = f * 16 + lr;
    float bias = bn1[n];
    #pragma unroll
    for (int r = 0; r < 4; ++r) {
      int m = m0 + lq * 4 + r;
      int node = n0 + m;
      if (node < N_NODES)
        h1[(long)node * 256 + n] = f2bf(silu_f(acc[f][r] + bias));
    }
  }
}

// ---------------------------------------------------------------------------
// Kernel 3: upd = h1 @ Wn2 + bn2; x = H + upd; out = LayerNorm(x)*g + b
// ---------------------------------------------------------------------------
__global__ __launch_bounds__(256, 1) void node2_kernel(
    const unsigned short* __restrict__ h1,
    const float* __restrict__ Wn2, const float* __restrict__ bn2,
    const float* __restrict__ H,
    const float* __restrict__ ln_g, const float* __restrict__ ln_b,
    float* __restrict__ out)
{
  __shared__ unsigned short As[64 * SA2];
  __shared__ unsigned short Ws[128 * SN2];  // Wn2^T [n][k], n=0..127, k=0..255

  const int tid  = threadIdx.x;
  const int lane = tid & 63;
  const int wv   = tid >> 6;
  const int lr   = lane & 15;
  const int lq   = lane >> 4;
  const int m0   = wv * 16;
  const int n0   = blockIdx.x * 64;

  {
    int n = tid & 127, half = tid >> 7;
    for (int k = half * 128; k < half * 128 + 128; ++k)
      Ws[n * SN2 + k] = f2bf(Wn2[k * 128 + n]);
  }
  {
    int le = tid >> 2, part = tid & 3;
    int node = n0 + le; if (node >= N_NODES) node = N_NODES - 1;
    const unsigned short* src = h1 + (long)node * 256 + part * 64;
    unsigned short* dst = &As[le * SA2 + part * 64];
    #pragma unroll
    for (int q = 0; q < 64; q += 8)
      *(bf16x8*)(dst + q) = *(const bf16x8*)(src + q);
  }
  __syncthreads();

  f32x4 zero4 = {0.f, 0.f, 0.f, 0.f};
  f32x4 acc[8];
  #pragma unroll
  for (int f = 0; f < 8; ++f) acc[f] = zero4;
  #pragma unroll
  for (int s = 0; s < 8; ++s) {
    int kb = s * 32 + lq * 8;
    bf16x8 a = *(const bf16x8*)&As[(m0 + lr) * SA2 + kb];
    #pragma unroll
    for (int f = 0; f < 8; ++f) {
      bf16x8 b = *(const bf16x8*)&Ws[(f * 16 + lr) * SN2 + kb];
      acc[f] = __builtin_amdgcn_mfma_f32_16x16x32_bf16(a, b, acc[f], 0, 0, 0);
    }
  }

  #pragma unroll
  for (int r = 0; r < 4; ++r) {
    int m = m0 + lq * 4 + r;
    int node = n0 + m;
    int nc = node < N_NODES ? node : N_NODES - 1;
    float x[8];
    float sum = 0.f, sumsq = 0.f;
    #pragma unroll
    for (int f = 0; f < 8; ++f) {
      int n = f * 16 + lr;
      float u = acc[f][r] + bn2[n];
      float xv = H[(long)nc * 128 + n] + u;
      x[f] = xv;
      sum += xv;
      sumsq += xv * xv;
    }
    #pragma unroll
    for (int o = 1; o < 16; o <<= 1) {
      sum   += __shfl_xor(sum, o);
      sumsq += __shfl_xor(sumsq, o);
    }
    float mu  = sum * (1.f / 128.f);
    float var = sumsq * (1.f / 128.f) - mu * mu;
    float rstd = rsqrtf(var + 1e-5f);
    if (node < N_NODES) {
      #pragma unroll
      for (int f = 0; f < 8; ++f) {
        int n = f * 16 + lr;
        out[(long)node * 128 + n] = (x[f] - mu) * rstd * ln_g[n] + ln_b[n];
      }
    }
  }
}

extern "C" void kernel_launch(void* const* d_in, const int* in_sizes, int n_in,
                              void* d_out, int out_size, void* d_ws, size_t ws_size,
                              hipStream_t stream) {
  const float* H       = (const float*)d_in[0];
  const float* xyz     = (const float*)d_in[1];
  const int*   eidx    = (const int*)d_in[2];
  const float* estruct = (const float*)d_in[3];
  const float* erest   = (const float*)d_in[4];
  const float* We1     = (const float*)d_in[5];
  const float* be1     = (const float*)d_in[6];
  const float* We2     = (const float*)d_in[7];
  const float* be2     = (const float*)d_in[8];
  const float* Wg1     = (const float*)d_in[9];
  const float* bg1     = (const float*)d_in[10];
  const float* Wg2     = (const float*)d_in[11];
  const float* bg2     = (const float*)d_in[12];
  const float* Wn1     = (const float*)d_in[13];
  const float* bn1     = (const float*)d_in[14];
  const float* Wn2     = (const float*)d_in[15];
  const float* bn2     = (const float*)d_in[16];
  const float* ln_g    = (const float*)d_in[17];
  const float* ln_b    = (const float*)d_in[18];

  float* agg = (float*)d_ws;                                        // 50000*64*4  = 12.8 MB
  unsigned short* h1 = (unsigned short*)((char*)d_ws + (size_t)N_NODES * 64 * 4);
                                                                    // 50000*256*2 = 25.6 MB
  float* out = (float*)d_out;

  hipMemsetAsync(agg, 0, (size_t)N_NODES * 64 * sizeof(float), stream);

  hipLaunchKernelGGL(edge_kernel, dim3(2048), dim3(256), 0, stream,
                     H, xyz, eidx, estruct, erest, We1, be1, We2, be2,
                     Wg1, bg1, Wg2, bg2, agg);
  hipLaunchKernelGGL(node1_kernel, dim3(NODE_TILES), dim3(256), 0, stream,
                     H, agg, Wn1, bn1, h1);
  hipLaunchKernelGGL(node2_kernel, dim3(NODE_TILES), dim3(256), 0, stream,
                     h1, Wn2, bn2, H, ln_g, ln_b, out);
}